// Round 1
// baseline (291.909 us; speedup 1.0000x reference)
//
#include <hip/hip_runtime.h>

// D = H = W = 128, NUM_STEPS = 7 (MONAI DVF2DDF scaling-and-squaring)
#define DD 128
constexpr int NV = DD * DD * DD;          // 2,097,152 voxels
constexpr float INV_SCALE = 1.0f / 128.0f; // 2^-NUM_STEPS

__device__ __forceinline__ void unpack_zyx(int tid, int& z, int& y, int& x) {
    x = tid & (DD - 1);
    y = (tid >> 7) & (DD - 1);
    z = tid >> 14;
}

__device__ __forceinline__ float clampd(float v) {
    return fminf(fmaxf(v, 0.0f), (float)(DD - 1));
}

// ---------------------------------------------------------------------------
// corner indices + weights for trilinear sample at clamped coords.
// Weight products kept in the exact same order as the verified kernel.
// ---------------------------------------------------------------------------
struct Corner {
    int i000, i001, i010, i011, i100, i101, i110, i111;
    float w000, w001, w010, w011, w100, w101, w110, w111;
};

__device__ __forceinline__ Corner make_corner(float cz, float cy, float cx) {
    Corner c;
    float z0f = floorf(cz), y0f = floorf(cy), x0f = floorf(cx);
    float wz = cz - z0f, wy = cy - y0f, wx = cx - x0f;
    int z0 = (int)z0f, y0 = (int)y0f, x0 = (int)x0f;
    // clamp handled via zero-delta at the high border (weight there is 0)
    int dx = (x0 < DD - 1) ? 1 : 0;
    int dy = (y0 < DD - 1) ? DD : 0;
    int dz = (z0 < DD - 1) ? DD * DD : 0;
    int i000 = (z0 << 14) + (y0 << 7) + x0;
    c.i000 = i000;           c.i001 = i000 + dx;
    c.i010 = i000 + dy;      c.i011 = i000 + dy + dx;
    c.i100 = i000 + dz;      c.i101 = i000 + dz + dx;
    c.i110 = i000 + dz + dy; c.i111 = i000 + dz + dy + dx;
    float omz = 1.0f - wz, omy = 1.0f - wy, omx = 1.0f - wx;
    c.w000 = omz * omy * omx; c.w001 = omz * omy * wx;
    c.w010 = omz * wy * omx;  c.w011 = omz * wy * wx;
    c.w100 = wz * omy * omx;  c.w101 = wz * omy * wx;
    c.w110 = wz * wy * omx;   c.w111 = wz * wy * wx;
    return c;
}

// ===========================================================================
// MAIN PATH (workspace >= 2 * NV * 16 bytes): float4-padded interleaved field
// ===========================================================================

// ---------------------------------------------------------------------------
// fused init + step 1 + dvf pass-through:
//   reads planar dvf once; writes dvf copy to out slot 3;
//   computes ddf1 = s*v + warp(s*v, s*v) sampling the RAW planar dvf and
//   scaling by 2^-7 afterwards (bit-exact: *2^-7 commutes with rounding).
// ---------------------------------------------------------------------------
__global__ __launch_bounds__(256)
void init_step1_kernel(const float* __restrict__ dvf,
                       float4* __restrict__ dst,
                       float* __restrict__ dvf_out) {
    int tid = blockIdx.x * blockDim.x + threadIdx.x;
    int z, y, x;
    unpack_zyx(tid, z, y, x);

    float v0 = dvf[tid];
    float v1 = dvf[tid + NV];
    float v2 = dvf[tid + 2 * NV];

    // pass-through (out slot 3 is free from the start in this path)
    dvf_out[tid]          = v0;
    dvf_out[tid + NV]     = v1;
    dvf_out[tid + 2 * NV] = v2;

    float d0 = v0 * INV_SCALE, d1 = v1 * INV_SCALE, d2 = v2 * INV_SCALE;

    float cz = clampd((float)z + d0);
    float cy = clampd((float)y + d1);
    float cx = clampd((float)x + d2);

    Corner c = make_corner(cz, cy, cx);
    const float* ch0 = dvf;
    const float* ch1 = dvf + NV;
    const float* ch2 = dvf + 2 * NV;

    float t0 = c.w000 * ch0[c.i000] + c.w001 * ch0[c.i001]
             + c.w010 * ch0[c.i010] + c.w011 * ch0[c.i011]
             + c.w100 * ch0[c.i100] + c.w101 * ch0[c.i101]
             + c.w110 * ch0[c.i110] + c.w111 * ch0[c.i111];
    float t1 = c.w000 * ch1[c.i000] + c.w001 * ch1[c.i001]
             + c.w010 * ch1[c.i010] + c.w011 * ch1[c.i011]
             + c.w100 * ch1[c.i100] + c.w101 * ch1[c.i101]
             + c.w110 * ch1[c.i110] + c.w111 * ch1[c.i111];
    float t2 = c.w000 * ch2[c.i000] + c.w001 * ch2[c.i001]
             + c.w010 * ch2[c.i010] + c.w011 * ch2[c.i011]
             + c.w100 * ch2[c.i100] + c.w101 * ch2[c.i101]
             + c.w110 * ch2[c.i110] + c.w111 * ch2[c.i111];

    dst[tid] = make_float4(t0 * INV_SCALE + d0,
                           t1 * INV_SCALE + d1,
                           t2 * INV_SCALE + d2, 0.0f);
}

// ---------------------------------------------------------------------------
// one squaring step on float4-padded field: dst = src + warp(src, src)
// every memory access is a single aligned global_load/store_dwordx4
// ---------------------------------------------------------------------------
template <bool PLANAR_OUT>
__global__ __launch_bounds__(256)
void step4_kernel(const float4* __restrict__ src,
                  float4* __restrict__ dst4,
                  float* __restrict__ dstp) {
    int tid = blockIdx.x * blockDim.x + threadIdx.x;
    int z, y, x;
    unpack_zyx(tid, z, y, x);

    float4 d = src[tid];

    float cz = clampd((float)z + d.x);
    float cy = clampd((float)y + d.y);
    float cx = clampd((float)x + d.z);

    Corner c = make_corner(cz, cy, cx);

    float4 v000 = src[c.i000], v001 = src[c.i001];
    float4 v010 = src[c.i010], v011 = src[c.i011];
    float4 v100 = src[c.i100], v101 = src[c.i101];
    float4 v110 = src[c.i110], v111 = src[c.i111];

    float r0 = c.w000 * v000.x + c.w001 * v001.x + c.w010 * v010.x + c.w011 * v011.x
             + c.w100 * v100.x + c.w101 * v101.x + c.w110 * v110.x + c.w111 * v111.x;
    float r1 = c.w000 * v000.y + c.w001 * v001.y + c.w010 * v010.y + c.w011 * v011.y
             + c.w100 * v100.y + c.w101 * v101.y + c.w110 * v110.y + c.w111 * v111.y;
    float r2 = c.w000 * v000.z + c.w001 * v001.z + c.w010 * v010.z + c.w011 * v011.z
             + c.w100 * v100.z + c.w101 * v101.z + c.w110 * v110.z + c.w111 * v111.z;

    r0 += d.x; r1 += d.y; r2 += d.z;

    if (PLANAR_OUT) {
        dstp[tid]          = r0;
        dstp[tid + NV]     = r1;
        dstp[tid + 2 * NV] = r2;
    } else {
        dst4[tid] = make_float4(r0, r1, r2, 0.0f);
    }
}

// ---------------------------------------------------------------------------
// final: read planar ddf; bilinear-warp moving_image, nearest-warp label.
// (dvf pass-through already done in init_step1_kernel on the main path)
// ---------------------------------------------------------------------------
__global__ __launch_bounds__(256)
void final_kernel(const float* __restrict__ ddf,
                  const float* __restrict__ mimg,
                  const float* __restrict__ mlab,
                  float* __restrict__ pred_img,
                  float* __restrict__ pred_lab) {
    int tid = blockIdx.x * blockDim.x + threadIdx.x;
    int z, y, x;
    unpack_zyx(tid, z, y, x);

    float d0 = ddf[tid];
    float d1 = ddf[tid + NV];
    float d2 = ddf[tid + 2 * NV];

    float cz = clampd((float)z + d0);
    float cy = clampd((float)y + d1);
    float cx = clampd((float)x + d2);

    Corner c = make_corner(cz, cy, cx);

    float v = c.w000 * mimg[c.i000] + c.w001 * mimg[c.i001]
            + c.w010 * mimg[c.i010] + c.w011 * mimg[c.i011]
            + c.w100 * mimg[c.i100] + c.w101 * mimg[c.i101]
            + c.w110 * mimg[c.i110] + c.w111 * mimg[c.i111];
    pred_img[tid] = v;

    int zi = (int)rintf(cz);
    int yi = (int)rintf(cy);
    int xi = (int)rintf(cx);
    pred_lab[tid] = mlab[(zi << 14) + (yi << 7) + xi];
}

// ===========================================================================
// FALLBACK PATH (workspace too small): previous verified 261 µs pipeline
// ===========================================================================

__device__ __forceinline__ void trilerp3(const float* __restrict__ src,
                                         float cz, float cy, float cx,
                                         float& r0, float& r1, float& r2) {
    Corner c = make_corner(cz, cy, cx);
    const float* p000 = src + 3 * c.i000;
    const float* p001 = src + 3 * c.i001;
    const float* p010 = src + 3 * c.i010;
    const float* p011 = src + 3 * c.i011;
    const float* p100 = src + 3 * c.i100;
    const float* p101 = src + 3 * c.i101;
    const float* p110 = src + 3 * c.i110;
    const float* p111 = src + 3 * c.i111;
    r0 = c.w000 * p000[0] + c.w001 * p001[0] + c.w010 * p010[0] + c.w011 * p011[0]
       + c.w100 * p100[0] + c.w101 * p101[0] + c.w110 * p110[0] + c.w111 * p111[0];
    r1 = c.w000 * p000[1] + c.w001 * p001[1] + c.w010 * p010[1] + c.w011 * p011[1]
       + c.w100 * p100[1] + c.w101 * p101[1] + c.w110 * p110[1] + c.w111 * p111[1];
    r2 = c.w000 * p000[2] + c.w001 * p001[2] + c.w010 * p010[2] + c.w011 * p011[2]
       + c.w100 * p100[2] + c.w101 * p101[2] + c.w110 * p110[2] + c.w111 * p111[2];
}

__global__ __launch_bounds__(256)
void init_kernel(const float* __restrict__ dvf, float* __restrict__ A) {
    int tid = blockIdx.x * blockDim.x + threadIdx.x;
    float d0 = dvf[tid] * INV_SCALE;
    float d1 = dvf[tid + NV] * INV_SCALE;
    float d2 = dvf[tid + 2 * NV] * INV_SCALE;
    float* p = A + 3 * tid;
    p[0] = d0; p[1] = d1; p[2] = d2;
}

template <bool PLANAR_OUT>
__global__ __launch_bounds__(256)
void step_kernel(const float* __restrict__ src, float* __restrict__ dst) {
    int tid = blockIdx.x * blockDim.x + threadIdx.x;
    int z, y, x;
    unpack_zyx(tid, z, y, x);
    const float* s = src + 3 * tid;
    float d0 = s[0], d1 = s[1], d2 = s[2];
    float cz = clampd((float)z + d0);
    float cy = clampd((float)y + d1);
    float cx = clampd((float)x + d2);
    float r0, r1, r2;
    trilerp3(src, cz, cy, cx, r0, r1, r2);
    r0 += d0; r1 += d1; r2 += d2;
    if (PLANAR_OUT) {
        dst[tid]          = r0;
        dst[tid + NV]     = r1;
        dst[tid + 2 * NV] = r2;
    } else {
        float* p = dst + 3 * tid;
        p[0] = r0; p[1] = r1; p[2] = r2;
    }
}

__global__ __launch_bounds__(256)
void final_kernel_fb(const float* __restrict__ ddf,
                     const float* __restrict__ mimg,
                     const float* __restrict__ mlab,
                     const float* __restrict__ dvf,
                     float* __restrict__ pred_img,
                     float* __restrict__ pred_lab,
                     float* __restrict__ dvf_out) {
    int tid = blockIdx.x * blockDim.x + threadIdx.x;
    int z, y, x;
    unpack_zyx(tid, z, y, x);
    float d0 = ddf[tid];
    float d1 = ddf[tid + NV];
    float d2 = ddf[tid + 2 * NV];
    float cz = clampd((float)z + d0);
    float cy = clampd((float)y + d1);
    float cx = clampd((float)x + d2);
    Corner c = make_corner(cz, cy, cx);
    float v = c.w000 * mimg[c.i000] + c.w001 * mimg[c.i001]
            + c.w010 * mimg[c.i010] + c.w011 * mimg[c.i011]
            + c.w100 * mimg[c.i100] + c.w101 * mimg[c.i101]
            + c.w110 * mimg[c.i110] + c.w111 * mimg[c.i111];
    pred_img[tid] = v;
    int zi = (int)rintf(cz);
    int yi = (int)rintf(cy);
    int xi = (int)rintf(cx);
    pred_lab[tid] = mlab[(zi << 14) + (yi << 7) + xi];
    dvf_out[tid]          = dvf[tid];
    dvf_out[tid + NV]     = dvf[tid + NV];
    dvf_out[tid + 2 * NV] = dvf[tid + 2 * NV];
}

// ===========================================================================

extern "C" void kernel_launch(void* const* d_in, const int* in_sizes, int n_in,
                              void* d_out, int out_size, void* d_ws, size_t ws_size,
                              hipStream_t stream) {
    const float* dvf  = (const float*)d_in[0];
    const float* mimg = (const float*)d_in[1];
    // d_in[2] = fixed_image: unused by the reference outputs
    const float* mlab = (const float*)d_in[3];

    float* out      = (float*)d_out;
    float* ddf_out  = out;              // slot 0: ddf  [3,D,H,W]
    float* pred_img = out + 3 * NV;     // slot 1
    float* pred_lab = out + 4 * NV;     // slot 2
    float* dvf_out  = out + 5 * NV;     // slot 3: dvf pass-through

    dim3 block(256);
    dim3 grid(NV / 256);  // 8192 blocks

    size_t need = (size_t)2 * NV * sizeof(float4);  // 64 MiB ping-pong
    if (d_ws != nullptr && ws_size >= need) {
        float4* A4 = (float4*)d_ws;
        float4* B4 = A4 + NV;
        // step 1 (fused with init + dvf pass-through) -> A4
        init_step1_kernel<<<grid, block, 0, stream>>>(dvf, A4, dvf_out);
        step4_kernel<false><<<grid, block, 0, stream>>>(A4, B4, nullptr); // 2
        step4_kernel<false><<<grid, block, 0, stream>>>(B4, A4, nullptr); // 3
        step4_kernel<false><<<grid, block, 0, stream>>>(A4, B4, nullptr); // 4
        step4_kernel<false><<<grid, block, 0, stream>>>(B4, A4, nullptr); // 5
        step4_kernel<false><<<grid, block, 0, stream>>>(A4, B4, nullptr); // 6
        step4_kernel<true ><<<grid, block, 0, stream>>>(B4, nullptr, ddf_out); // 7
        final_kernel<<<grid, block, 0, stream>>>(ddf_out, mimg, mlab,
                                                 pred_img, pred_lab);
    } else {
        // fallback: previous verified pipeline (scratch inside d_out)
        float* A = dvf_out;
        float* B = ddf_out;
        init_kernel<<<grid, block, 0, stream>>>(dvf, A);
        step_kernel<false><<<grid, block, 0, stream>>>(A, B);  // 1
        step_kernel<false><<<grid, block, 0, stream>>>(B, A);  // 2
        step_kernel<false><<<grid, block, 0, stream>>>(A, B);  // 3
        step_kernel<false><<<grid, block, 0, stream>>>(B, A);  // 4
        step_kernel<false><<<grid, block, 0, stream>>>(A, B);  // 5
        step_kernel<false><<<grid, block, 0, stream>>>(B, A);  // 6
        step_kernel<true ><<<grid, block, 0, stream>>>(A, B);  // 7
        final_kernel_fb<<<grid, block, 0, stream>>>(B, mimg, mlab, dvf,
                                                    pred_img, pred_lab, dvf_out);
    }
}